// Round 12
// baseline (404.497 us; speedup 1.0000x reference)
//
#include <hip/hip_runtime.h>
#include <hip/hip_bf16.h>
#include <hip/hip_fp16.h>

#define N_NODES 100000
#define N_EDGES 3200000
#define NB      100
#define NPG     1000
#define EPG     32000    // edges per graph
#define DIN     128
#define DH      64
#define DE      32
#define NCLS    10

// XCD-affine swizzle: graph g lives on XCD g%8 (blockIdx%8 = dispatch
// round-robin), keeping each graph's working set in ONE XCD's 4MB L2.
// Aggregation = node-per-wave PULL gather from L2 (R7). R9/R10: single-kernel
// LDS counting sort. R11: fp16 gather rows (halved L2 stream; agg128 101->72).
// R12: (a) 32-bit gather offsets (R11 showed VALUBusy ~70% -- 64-bit addr
// math per load was a chunk of it); (b) a1|x1 buffer fp16 (write 50->25MB);
// (c) smax+pool+head fused into k_tail (two fewer launches, one less s2 pass).

// ---------------- Per-graph CSR build, entirely in LDS ----------------

__global__ __launch_bounds__(1024) void k_sort(const int* __restrict__ src,
                                               const int* __restrict__ dst,
                                               int* __restrict__ rowptr,
                                               float* __restrict__ dinv,
                                               unsigned short* __restrict__ ssrc) {
    __shared__ __align__(16) unsigned short buf[EPG];  // 64 KB sorted output
    __shared__ int cnt[NPG];
    __shared__ int pre[NPG];
    __shared__ int sm[1024];
    int g = (blockIdx.x & 7) + 8 * (blockIdx.x >> 3);
    if (g >= NB) return;
    int t = threadIdx.x;
    int ebase = g * EPG, nbase = g * NPG;
    if (t < NPG) cnt[t] = 0;
    __syncthreads();
    for (int i = t; i < EPG; i += 1024)
        atomicAdd(&cnt[dst[ebase + i] - nbase], 1);
    __syncthreads();
    int v = (t < NPG) ? cnt[t] : 0;
    if (t < NPG) dinv[nbase + t] = rsqrtf((float)v + 2.0f);
    sm[t] = v;
    __syncthreads();
    for (int off = 1; off < 1024; off <<= 1) {
        int x = (t >= off) ? sm[t - off] : 0;
        __syncthreads();
        sm[t] += x;
        __syncthreads();
    }
    if (t < NPG) {
        int ex = sm[t] - v;
        pre[t] = ex;
        rowptr[nbase + t] = ebase + ex;
    }
    if (g == NB - 1 && t == 0) rowptr[N_NODES] = N_EDGES;
    __syncthreads();
    for (int i = t; i < EPG; i += 1024) {
        int e = ebase + i;
        int d = dst[e] - nbase;
        int s = src[e] - nbase;
        int pos = atomicAdd(&pre[d], 1);
        buf[pos] = (unsigned short)s;
    }
    __syncthreads();
    uint4* gout = (uint4*)(ssrc + ebase);
    const uint4* lbuf = (const uint4*)buf;
    for (int i = t; i < EPG / 8; i += 1024)
        gout[i] = lbuf[i];
}

// ---------------- GEMM 1: h16 = fp16( x @ [W_a1 | W_x1] ) ----------------

__global__ __launch_bounds__(256) void k_gemm1(const float* __restrict__ x,
                                               const float* __restrict__ Wa,
                                               const float* __restrict__ Wx,
                                               unsigned short* __restrict__ h16) {
    __shared__ float xs[32][128];
    __shared__ float ws[32][128];
    int xcd = blockIdx.x & 7, slot = blockIdx.x >> 3;
    int g = xcd + 8 * (slot >> 5);
    int chunk = slot & 31;
    if (g >= NB) return;
    int row0 = g * NPG + chunk * 32;
    int t = threadIdx.x;
    for (int i = 0; i < 4; i++) {
        int idx = t + 256 * i;
        int r = idx >> 5, k4 = idx & 31;
        int rr = row0 + r; if (rr >= N_NODES) rr = N_NODES - 1;
        *(float4*)&xs[r][k4 * 4] = *(const float4*)&x[(size_t)rr * 128 + k4 * 4];
    }
    float acc[4][4] = {};
    int rg = t >> 5, cg = t & 31;
    for (int kt = 0; kt < 4; kt++) {
        __syncthreads();
        for (int i = 0; i < 4; i++) {
            int idx = t + 256 * i;
            int kk = idx >> 5, c4 = idx & 31;
            int k = kt * 32 + kk, c = c4 * 4;
            float4 v;
            if (c < 64) v = *(const float4*)&Wa[k * 64 + c];
            else        v = *(const float4*)&Wx[k * 64 + (c - 64)];
            *(float4*)&ws[kk][c] = v;
        }
        __syncthreads();
        for (int kk = 0; kk < 32; kk++) {
            float4 w = *(float4*)&ws[kk][cg * 4];
            float xv[4];
            for (int i = 0; i < 4; i++) xv[i] = xs[rg * 4 + i][kt * 32 + kk];
            for (int i = 0; i < 4; i++) {
                acc[i][0] += xv[i] * w.x; acc[i][1] += xv[i] * w.y;
                acc[i][2] += xv[i] * w.z; acc[i][3] += xv[i] * w.w;
            }
        }
    }
    for (int i = 0; i < 4; i++) {
        int r = row0 + rg * 4 + i;
        if (r < N_NODES) {
            union { ushort4 u; __half2 h[2]; } pk;
            pk.h[0] = __floats2half2_rn(acc[i][0], acc[i][1]);
            pk.h[1] = __floats2half2_rn(acc[i][2], acc[i][3]);
            *(ushort4*)&h16[r * 128 + cg * 4] = pk.u;
        }
    }
}

// ---------------- Aggregation, 128 channels (layer 1), fp16 gather ----------------
// Wave = 1 node. Lane = (sub 0..3 edge-parallel, cl 0..15 8-ch 16B group).
// All offsets 32-bit (SGPR base + voffset loads). Output packed fp16.

__global__ __launch_bounds__(256) void k_agg128(const unsigned short* __restrict__ h16,
                                                const int* __restrict__ rowptr,
                                                const unsigned short* __restrict__ ssrc,
                                                const float* __restrict__ dinv,
                                                const float* __restrict__ ba,
                                                const float* __restrict__ bx,
                                                unsigned short* __restrict__ outB16) {
    int xcd = blockIdx.x & 7, slot = blockIdx.x >> 3;
    int gi = slot / 250, chunk = slot - gi * 250;
    int g = xcd + 8 * gi;
    if (g >= NB) return;
    int nl   = chunk * 4 + (threadIdx.x >> 6);   // local node 0..999
    int wid  = g * NPG + nl;
    int lane = threadIdx.x & 63;
    int sub = lane >> 4;           // 0..3: edge j%4
    int cl8 = (lane & 15) * 8;     // channel offset of this lane's 16B group
    const unsigned short* hg = h16 + g * NPG * 128;
    const float* dvg = dinv + g * NPG;
    float acc[8] = {};
    union U8 { uint4 u; __half2 h[4]; };
    int e0 = rowptr[wid], e1 = rowptr[wid + 1];
    int e = e0;
    for (; e + 16 <= e1; e += 16) {
        int s[4]; float dv[4]; U8 r[4];
        #pragma unroll
        for (int j = 0; j < 4; j++) s[j] = ssrc[e + 4 * j + sub];
        #pragma unroll
        for (int j = 0; j < 4; j++) dv[j] = dvg[s[j]];     // broadcast
        #pragma unroll
        for (int j = 0; j < 4; j++) r[j].u = *(const uint4*)&hg[s[j] * 128 + cl8];
        #pragma unroll
        for (int j = 0; j < 4; j++) {
            #pragma unroll
            for (int k = 0; k < 4; k++) {
                float2 f = __half22float2(r[j].h[k]);
                acc[2 * k]     += dv[j] * f.x;
                acc[2 * k + 1] += dv[j] * f.y;
            }
        }
    }
    for (; e + 8 <= e1; e += 8) {
        #pragma unroll
        for (int j = 0; j < 2; j++) {
            int ss = ssrc[e + 4 * j + sub];
            float dv = dvg[ss];
            U8 r; r.u = *(const uint4*)&hg[ss * 128 + cl8];
            #pragma unroll
            for (int k = 0; k < 4; k++) {
                float2 f = __half22float2(r.h[k]);
                acc[2 * k]     += dv * f.x;
                acc[2 * k + 1] += dv * f.y;
            }
        }
    }
    for (; e < e1; e += 4) {
        int ee = e + sub;
        int ss; float dv;
        if (ee < e1) { ss = ssrc[ee]; dv = dvg[ss]; }
        else         { ss = ssrc[e];  dv = 0.0f; }
        U8 r; r.u = *(const uint4*)&hg[ss * 128 + cl8];
        #pragma unroll
        for (int k = 0; k < 4; k++) {
            float2 f = __half22float2(r.h[k]);
            acc[2 * k]     += dv * f.x;
            acc[2 * k + 1] += dv * f.y;
        }
    }
    #pragma unroll
    for (int k = 0; k < 8; k++) {
        acc[k] += __shfl_xor(acc[k], 16);
        acc[k] += __shfl_xor(acc[k], 32);
    }
    if (sub == 0) {
        float di = dvg[nl];
        float sw = 2.0f * di * di;
        U8 hv; hv.u = *(const uint4*)&hg[nl * 128 + cl8];
        const float* bb = (cl8 < 64) ? &ba[cl8] : &bx[cl8 - 64];
        U8 pk;
        #pragma unroll
        for (int k = 0; k < 4; k++) {
            float2 f = __half22float2(hv.h[k]);
            float ox = fmaxf(di * acc[2 * k]     + sw * f.x + bb[2 * k],     0.0f);
            float oy = fmaxf(di * acc[2 * k + 1] + sw * f.y + bb[2 * k + 1], 0.0f);
            pk.h[k] = __floats2half2_rn(ox, oy);
        }
        *(uint4*)&outB16[wid * 128 + cl8] = pk.u;
    }
}

// ---------------- Aggregation, 64 channels (layer 2), fp16 gather ----------------
// Lane = (sub 0..7 edge-parallel, cl 0..7 8-ch group). 32-bit offsets.
// cg<32: a-branch (+b_a2, no relu); cg>=32: x-branch (+b_x2, relu). fp32 out.

__global__ __launch_bounds__(256) void k_agg64(const unsigned short* __restrict__ g16,
                                               const int* __restrict__ rowptr,
                                               const unsigned short* __restrict__ ssrc,
                                               const float* __restrict__ dinv,
                                               const float* __restrict__ ba2,
                                               const float* __restrict__ bx2,
                                               float* __restrict__ s2) {
    int xcd = blockIdx.x & 7, slot = blockIdx.x >> 3;
    int gi = slot / 250, chunk = slot - gi * 250;
    int g = xcd + 8 * gi;
    if (g >= NB) return;
    int nl   = chunk * 4 + (threadIdx.x >> 6);
    int wid  = g * NPG + nl;
    int lane = threadIdx.x & 63;
    int sub = lane >> 3;           // 0..7: edge j%8
    int cl8 = (lane & 7) * 8;      // channel offset
    const unsigned short* hg = g16 + g * NPG * 64;
    const float* dvg = dinv + g * NPG;
    float acc[8] = {};
    union U8 { uint4 u; __half2 h[4]; };
    int e0 = rowptr[wid], e1 = rowptr[wid + 1];
    int e = e0;
    for (; e + 16 <= e1; e += 16) {
        int s[2]; float dv[2]; U8 r[2];
        #pragma unroll
        for (int j = 0; j < 2; j++) s[j] = ssrc[e + 8 * j + sub];
        #pragma unroll
        for (int j = 0; j < 2; j++) dv[j] = dvg[s[j]];
        #pragma unroll
        for (int j = 0; j < 2; j++) r[j].u = *(const uint4*)&hg[s[j] * 64 + cl8];
        #pragma unroll
        for (int j = 0; j < 2; j++) {
            #pragma unroll
            for (int k = 0; k < 4; k++) {
                float2 f = __half22float2(r[j].h[k]);
                acc[2 * k]     += dv[j] * f.x;
                acc[2 * k + 1] += dv[j] * f.y;
            }
        }
    }
    for (; e < e1; e += 8) {
        int ee = e + sub;
        int ss; float dv;
        if (ee < e1) { ss = ssrc[ee]; dv = dvg[ss]; }
        else         { ss = ssrc[e];  dv = 0.0f; }
        U8 r; r.u = *(const uint4*)&hg[ss * 64 + cl8];
        #pragma unroll
        for (int k = 0; k < 4; k++) {
            float2 f = __half22float2(r.h[k]);
            acc[2 * k]     += dv * f.x;
            acc[2 * k + 1] += dv * f.y;
        }
    }
    #pragma unroll
    for (int k = 0; k < 8; k++) {
        acc[k] += __shfl_xor(acc[k], 8);
        acc[k] += __shfl_xor(acc[k], 16);
        acc[k] += __shfl_xor(acc[k], 32);
    }
    if (sub == 0) {
        float di = dvg[nl];
        float sw = 2.0f * di * di;
        U8 hv; hv.u = *(const uint4*)&hg[nl * 64 + cl8];
        float o[8];
        #pragma unroll
        for (int k = 0; k < 4; k++) {
            float2 f = __half22float2(hv.h[k]);
            o[2 * k]     = di * acc[2 * k]     + sw * f.x;
            o[2 * k + 1] = di * acc[2 * k + 1] + sw * f.y;
        }
        if (cl8 < 32) {
            #pragma unroll
            for (int k = 0; k < 8; k++) o[k] += ba2[cl8 + k];
        } else {
            #pragma unroll
            for (int k = 0; k < 8; k++) o[k] = fmaxf(o[k] + bx2[cl8 - 32 + k], 0.0f);
        }
        *(float4*)&s2[wid * 64 + cl8]     = make_float4(o[0], o[1], o[2], o[3]);
        *(float4*)&s2[wid * 64 + cl8 + 4] = make_float4(o[4], o[5], o[6], o[7]);
    }
}

// ---------------- GEMM 2: g16 = fp16( [a1|x1] @ blockdiag(W_a2, W_x2) ) ----------------
// Input Bm16 is fp16 (converted to fp32 while staging to LDS).

__global__ __launch_bounds__(256) void k_gemm2(const unsigned short* __restrict__ Bm16,
                                               const float* __restrict__ Wa2,
                                               const float* __restrict__ Wx2,
                                               unsigned short* __restrict__ g16) {
    __shared__ float xs[64][132];
    __shared__ float ws[64][68];
    int xcd = blockIdx.x & 7, slot = blockIdx.x >> 3;
    int g = xcd + 8 * (slot >> 4);
    int chunk = slot & 15;
    if (g >= NB) return;
    int row0 = g * NPG + chunk * 64;   // chunk 15 spills into next graph: benign dup
    int t = threadIdx.x;
    for (int i = 0; i < 4; i++) {
        int idx = t + 256 * i;
        int k = idx >> 4, c4 = idx & 15, c = c4 * 4;
        float4 v;
        if (c < 32) v = *(const float4*)&Wa2[k * 32 + c];
        else        v = *(const float4*)&Wx2[k * 32 + (c - 32)];
        *(float4*)&ws[k][c] = v;
    }
    for (int i = 0; i < 4; i++) {
        int idx = t + 256 * i;          // 1024 uint4s = 64 rows x 16 groups
        int r = idx >> 4, c8 = idx & 15;
        int rr = row0 + r; if (rr >= N_NODES) rr = N_NODES - 1;
        union { uint4 u; __half2 h[4]; } pk;
        pk.u = *(const uint4*)&Bm16[rr * 128 + c8 * 8];
        float2 f0 = __half22float2(pk.h[0]);
        float2 f1 = __half22float2(pk.h[1]);
        float2 f2 = __half22float2(pk.h[2]);
        float2 f3 = __half22float2(pk.h[3]);
        int cb = c8 * 8;
        *(float4*)&xs[r][cb]     = make_float4(f0.x, f0.y, f1.x, f1.y);
        *(float4*)&xs[r][cb + 4] = make_float4(f2.x, f2.y, f3.x, f3.y);
    }
    __syncthreads();
    int cg = t & 15, rg = t >> 4;
    int koff = (cg < 8) ? 0 : 64;
    float acc[4][4] = {};
    for (int k = 0; k < 64; k++) {
        float4 w = *(float4*)&ws[k][cg * 4];
        float xv[4];
        for (int i = 0; i < 4; i++) xv[i] = xs[rg * 4 + i][koff + k];
        for (int i = 0; i < 4; i++) {
            acc[i][0] += xv[i] * w.x; acc[i][1] += xv[i] * w.y;
            acc[i][2] += xv[i] * w.z; acc[i][3] += xv[i] * w.w;
        }
    }
    for (int i = 0; i < 4; i++) {
        int r = row0 + rg * 4 + i;
        if (r < N_NODES) {
            union { ushort4 u; __half2 h[2]; } pk;
            pk.h[0] = __floats2half2_rn(acc[i][0], acc[i][1]);
            pk.h[1] = __floats2half2_rn(acc[i][2], acc[i][3]);
            *(ushort4*)&g16[r * 64 + cg * 4] = pk.u;
        }
    }
}

// ---------------- Fused tail: segment-softmax stats + bilinear pool + head ----------------
// One block per graph. Pass 1: per-channel max & exp-sum over the a-branch.
// Pass 2: outer product sum_n exp(a[n,e]-m_e) * x[n,f] (exp at staging).
// Pass 3: (sinv .* prods) @ Wlin + blin -> softmax -> out[g].

__global__ __launch_bounds__(256) void k_tail(const float* __restrict__ s2,
                                              const float* __restrict__ Wlin,
                                              const float* __restrict__ blin,
                                              float* __restrict__ out) {
    __shared__ float ta[50][32];
    __shared__ float tx[50][32];
    __shared__ float gm[32];
    __shared__ float si[32];
    __shared__ float red8[8][32];
    __shared__ float hred[4][NCLS];
    int g = (blockIdx.x & 7) + 8 * (blockIdx.x >> 3);
    if (g >= NB) return;
    int t = threadIdx.x;
    const float* sg = s2 + (size_t)g * NPG * 64;
    // pass 1: max then exp-sum over a-channels (c = 0..31)
    int c = t & 31, sub = t >> 5;
    float m = -1e30f;
    for (int n = sub; n < NPG; n += 8)
        m = fmaxf(m, sg[n * 64 + c]);
    red8[sub][c] = m; __syncthreads();
    if (sub == 0) {
        for (int j = 1; j < 8; j++) m = fmaxf(m, red8[j][c]);
        gm[c] = m;
    }
    __syncthreads();
    m = gm[c];
    float sum = 0.0f;
    for (int n = sub; n < NPG; n += 8)
        sum += __expf(sg[n * 64 + c] - m);
    __syncthreads();
    red8[sub][c] = sum; __syncthreads();
    if (sub == 0) {
        for (int j = 1; j < 8; j++) sum += red8[j][c];
        si[c] = 1.0f / sum;
    }
    __syncthreads();
    // pass 2: pooled outer product, exp applied at staging
    int e  = t >> 3;
    int f4 = t & 7;
    float a0 = 0.f, a1 = 0.f, a2 = 0.f, a3 = 0.f;
    for (int n0 = 0; n0 < NPG; n0 += 50) {
        __syncthreads();
        for (int i = t; i < 50 * 16; i += 256) {
            int r = i >> 4, c4 = i & 15;
            float4 v = *(const float4*)&sg[(n0 + r) * 64 + c4 * 4];
            if (c4 < 8) {
                int cb = c4 * 4;
                v.x = __expf(v.x - gm[cb + 0]);
                v.y = __expf(v.y - gm[cb + 1]);
                v.z = __expf(v.z - gm[cb + 2]);
                v.w = __expf(v.w - gm[cb + 3]);
                *(float4*)&ta[r][cb] = v;
            } else {
                *(float4*)&tx[r][(c4 - 8) * 4] = v;
            }
        }
        __syncthreads();
        #pragma unroll 5
        for (int n = 0; n < 50; n++) {
            float a   = ta[n][e];
            float4 xv = *(float4*)&tx[n][f4 * 4];
            a0 += a * xv.x; a1 += a * xv.y; a2 += a * xv.z; a3 += a * xv.w;
        }
    }
    // pass 3: head
    float p[NCLS];
    for (int cc = 0; cc < NCLS; cc++) p[cc] = 0.0f;
    float sie = si[e];
    float acc4[4] = {a0, a1, a2, a3};
    for (int j = 0; j < 4; j++) {
        int k = e * 32 + f4 * 4 + j;
        float v = acc4[j] * sie;
        const float* wrow = &Wlin[k * NCLS];
        for (int cc = 0; cc < NCLS; cc++) p[cc] += v * wrow[cc];
    }
    for (int off = 32; off > 0; off >>= 1)
        for (int cc = 0; cc < NCLS; cc++) p[cc] += __shfl_down(p[cc], off, 64);
    int wave = t >> 6, lane = t & 63;
    if (lane == 0)
        for (int cc = 0; cc < NCLS; cc++) hred[wave][cc] = p[cc];
    __syncthreads();
    if (t == 0) {
        float logits[NCLS]; float mx = -1e30f;
        for (int cc = 0; cc < NCLS; cc++) {
            logits[cc] = hred[0][cc] + hred[1][cc] + hred[2][cc] + hred[3][cc] + blin[cc];
            mx = fmaxf(mx, logits[cc]);
        }
        float s = 0.0f;
        for (int cc = 0; cc < NCLS; cc++) { logits[cc] = expf(logits[cc] - mx); s += logits[cc]; }
        float inv = 1.0f / s;
        for (int cc = 0; cc < NCLS; cc++) out[g * NCLS + cc] = logits[cc] * inv;
    }
}

// ---------------- launch ----------------

extern "C" void kernel_launch(void* const* d_in, const int* in_sizes, int n_in,
                              void* d_out, int out_size, void* d_ws, size_t ws_size,
                              hipStream_t stream) {
    const float* x    = (const float*)d_in[0];
    const int*   ei   = (const int*)d_in[1];
    const float* Wa1  = (const float*)d_in[3];
    const float* ba1  = (const float*)d_in[4];
    const float* Wa2  = (const float*)d_in[5];
    const float* ba2  = (const float*)d_in[6];
    const float* Wx1  = (const float*)d_in[7];
    const float* bx1  = (const float*)d_in[8];
    const float* Wx2  = (const float*)d_in[9];
    const float* bx2  = (const float*)d_in[10];
    const float* Wlin = (const float*)d_in[11];
    const float* blin = (const float*)d_in[12];
    float* out = (float*)d_out;

    char* w = (char*)d_ws;
    auto alloc = [&](size_t bytes) -> void* {
        void* p = (void*)w;
        w += (bytes + 255) & ~(size_t)255;
        return p;
    };
    int*            rowptr = (int*)alloc((N_NODES + 1) * sizeof(int));
    float*          dinv   = (float*)alloc(N_NODES * sizeof(float));
    unsigned short* ssrc   = (unsigned short*)alloc((size_t)N_EDGES * sizeof(unsigned short));
    unsigned short* h16    = (unsigned short*)alloc((size_t)N_NODES * 128 * sizeof(unsigned short));
    unsigned short* b16    = (unsigned short*)alloc((size_t)N_NODES * 128 * sizeof(unsigned short));
    unsigned short* g16    = (unsigned short*)alloc((size_t)N_NODES * 64 * sizeof(unsigned short));
    float*          s2     = (float*)alloc((size_t)N_NODES * 64 * sizeof(float));

    const int* srcp = ei;
    const int* dstp = ei + N_EDGES;

    k_sort<<<8 * 13, 1024, 0, stream>>>(srcp, dstp, rowptr, dinv, ssrc);
    k_gemm1<<<8 * 13 * 32, 256, 0, stream>>>(x, Wa1, Wx1, h16);
    k_agg128<<<8 * 13 * 250, 256, 0, stream>>>(h16, rowptr, ssrc, dinv, ba1, bx1, b16);
    k_gemm2<<<8 * 13 * 16, 256, 0, stream>>>(b16, Wa2, Wx2, g16);
    k_agg64<<<8 * 13 * 250, 256, 0, stream>>>(g16, rowptr, ssrc, dinv, ba2, bx2, s2);
    k_tail<<<8 * 13, 256, 0, stream>>>(s2, Wlin, blin, out);
}

// Round 13
// 350.207 us; speedup vs baseline: 1.1550x; 1.1550x over previous
//
#include <hip/hip_runtime.h>
#include <hip/hip_bf16.h>
#include <hip/hip_fp16.h>

#define N_NODES 100000
#define N_EDGES 3200000
#define NB      100
#define NPG     1000
#define EPG     32000    // edges per graph
#define DIN     128
#define DH      64
#define DE      32
#define NCLS    10

// XCD-affine swizzle: graph g lives on XCD g%8 (blockIdx%8 = dispatch
// round-robin), keeping each graph's working set in ONE XCD's 4MB L2.
// Aggregation = node-per-wave PULL gather from L2 (R7). R9/R10: single-kernel
// LDS counting sort. R11: fp16 gather rows. R12: 32-bit gather offsets +
// fp16 a1|x1 buffer (non-tail pipeline -45us) BUT fused k_tail regressed
// (88.9us @ 4% occupancy -- 100 monolithic blocks can't hide L2 latency).
// R13: un-fused tail with MORE parallelism than R11: smax 512thr,
// pool 8 chunks/graph (832 blocks), head sums 8 partials.

// ---------------- Per-graph CSR build, entirely in LDS ----------------

__global__ __launch_bounds__(1024) void k_sort(const int* __restrict__ src,
                                               const int* __restrict__ dst,
                                               int* __restrict__ rowptr,
                                               float* __restrict__ dinv,
                                               unsigned short* __restrict__ ssrc) {
    __shared__ __align__(16) unsigned short buf[EPG];  // 64 KB sorted output
    __shared__ int cnt[NPG];
    __shared__ int pre[NPG];
    __shared__ int sm[1024];
    int g = (blockIdx.x & 7) + 8 * (blockIdx.x >> 3);
    if (g >= NB) return;
    int t = threadIdx.x;
    int ebase = g * EPG, nbase = g * NPG;
    if (t < NPG) cnt[t] = 0;
    __syncthreads();
    for (int i = t; i < EPG; i += 1024)
        atomicAdd(&cnt[dst[ebase + i] - nbase], 1);
    __syncthreads();
    int v = (t < NPG) ? cnt[t] : 0;
    if (t < NPG) dinv[nbase + t] = rsqrtf((float)v + 2.0f);
    sm[t] = v;
    __syncthreads();
    for (int off = 1; off < 1024; off <<= 1) {
        int x = (t >= off) ? sm[t - off] : 0;
        __syncthreads();
        sm[t] += x;
        __syncthreads();
    }
    if (t < NPG) {
        int ex = sm[t] - v;
        pre[t] = ex;
        rowptr[nbase + t] = ebase + ex;
    }
    if (g == NB - 1 && t == 0) rowptr[N_NODES] = N_EDGES;
    __syncthreads();
    for (int i = t; i < EPG; i += 1024) {
        int e = ebase + i;
        int d = dst[e] - nbase;
        int s = src[e] - nbase;
        int pos = atomicAdd(&pre[d], 1);
        buf[pos] = (unsigned short)s;
    }
    __syncthreads();
    uint4* gout = (uint4*)(ssrc + ebase);
    const uint4* lbuf = (const uint4*)buf;
    for (int i = t; i < EPG / 8; i += 1024)
        gout[i] = lbuf[i];
}

// ---------------- GEMM 1: h16 = fp16( x @ [W_a1 | W_x1] ) ----------------

__global__ __launch_bounds__(256) void k_gemm1(const float* __restrict__ x,
                                               const float* __restrict__ Wa,
                                               const float* __restrict__ Wx,
                                               unsigned short* __restrict__ h16) {
    __shared__ float xs[32][128];
    __shared__ float ws[32][128];
    int xcd = blockIdx.x & 7, slot = blockIdx.x >> 3;
    int g = xcd + 8 * (slot >> 5);
    int chunk = slot & 31;
    if (g >= NB) return;
    int row0 = g * NPG + chunk * 32;
    int t = threadIdx.x;
    for (int i = 0; i < 4; i++) {
        int idx = t + 256 * i;
        int r = idx >> 5, k4 = idx & 31;
        int rr = row0 + r; if (rr >= N_NODES) rr = N_NODES - 1;
        *(float4*)&xs[r][k4 * 4] = *(const float4*)&x[(size_t)rr * 128 + k4 * 4];
    }
    float acc[4][4] = {};
    int rg = t >> 5, cg = t & 31;
    for (int kt = 0; kt < 4; kt++) {
        __syncthreads();
        for (int i = 0; i < 4; i++) {
            int idx = t + 256 * i;
            int kk = idx >> 5, c4 = idx & 31;
            int k = kt * 32 + kk, c = c4 * 4;
            float4 v;
            if (c < 64) v = *(const float4*)&Wa[k * 64 + c];
            else        v = *(const float4*)&Wx[k * 64 + (c - 64)];
            *(float4*)&ws[kk][c] = v;
        }
        __syncthreads();
        for (int kk = 0; kk < 32; kk++) {
            float4 w = *(float4*)&ws[kk][cg * 4];
            float xv[4];
            for (int i = 0; i < 4; i++) xv[i] = xs[rg * 4 + i][kt * 32 + kk];
            for (int i = 0; i < 4; i++) {
                acc[i][0] += xv[i] * w.x; acc[i][1] += xv[i] * w.y;
                acc[i][2] += xv[i] * w.z; acc[i][3] += xv[i] * w.w;
            }
        }
    }
    for (int i = 0; i < 4; i++) {
        int r = row0 + rg * 4 + i;
        if (r < N_NODES) {
            union { ushort4 u; __half2 h[2]; } pk;
            pk.h[0] = __floats2half2_rn(acc[i][0], acc[i][1]);
            pk.h[1] = __floats2half2_rn(acc[i][2], acc[i][3]);
            *(ushort4*)&h16[r * 128 + cg * 4] = pk.u;
        }
    }
}

// ---------------- Aggregation, 128 channels (layer 1), fp16 gather ----------------

__global__ __launch_bounds__(256) void k_agg128(const unsigned short* __restrict__ h16,
                                                const int* __restrict__ rowptr,
                                                const unsigned short* __restrict__ ssrc,
                                                const float* __restrict__ dinv,
                                                const float* __restrict__ ba,
                                                const float* __restrict__ bx,
                                                unsigned short* __restrict__ outB16) {
    int xcd = blockIdx.x & 7, slot = blockIdx.x >> 3;
    int gi = slot / 250, chunk = slot - gi * 250;
    int g = xcd + 8 * gi;
    if (g >= NB) return;
    int nl   = chunk * 4 + (threadIdx.x >> 6);   // local node 0..999
    int wid  = g * NPG + nl;
    int lane = threadIdx.x & 63;
    int sub = lane >> 4;           // 0..3: edge j%4
    int cl8 = (lane & 15) * 8;     // channel offset of this lane's 16B group
    const unsigned short* hg = h16 + g * NPG * 128;
    const float* dvg = dinv + g * NPG;
    float acc[8] = {};
    union U8 { uint4 u; __half2 h[4]; };
    int e0 = rowptr[wid], e1 = rowptr[wid + 1];
    int e = e0;
    for (; e + 16 <= e1; e += 16) {
        int s[4]; float dv[4]; U8 r[4];
        #pragma unroll
        for (int j = 0; j < 4; j++) s[j] = ssrc[e + 4 * j + sub];
        #pragma unroll
        for (int j = 0; j < 4; j++) dv[j] = dvg[s[j]];     // broadcast
        #pragma unroll
        for (int j = 0; j < 4; j++) r[j].u = *(const uint4*)&hg[s[j] * 128 + cl8];
        #pragma unroll
        for (int j = 0; j < 4; j++) {
            #pragma unroll
            for (int k = 0; k < 4; k++) {
                float2 f = __half22float2(r[j].h[k]);
                acc[2 * k]     += dv[j] * f.x;
                acc[2 * k + 1] += dv[j] * f.y;
            }
        }
    }
    for (; e + 8 <= e1; e += 8) {
        #pragma unroll
        for (int j = 0; j < 2; j++) {
            int ss = ssrc[e + 4 * j + sub];
            float dv = dvg[ss];
            U8 r; r.u = *(const uint4*)&hg[ss * 128 + cl8];
            #pragma unroll
            for (int k = 0; k < 4; k++) {
                float2 f = __half22float2(r.h[k]);
                acc[2 * k]     += dv * f.x;
                acc[2 * k + 1] += dv * f.y;
            }
        }
    }
    for (; e < e1; e += 4) {
        int ee = e + sub;
        int ss; float dv;
        if (ee < e1) { ss = ssrc[ee]; dv = dvg[ss]; }
        else         { ss = ssrc[e];  dv = 0.0f; }
        U8 r; r.u = *(const uint4*)&hg[ss * 128 + cl8];
        #pragma unroll
        for (int k = 0; k < 4; k++) {
            float2 f = __half22float2(r.h[k]);
            acc[2 * k]     += dv * f.x;
            acc[2 * k + 1] += dv * f.y;
        }
    }
    #pragma unroll
    for (int k = 0; k < 8; k++) {
        acc[k] += __shfl_xor(acc[k], 16);
        acc[k] += __shfl_xor(acc[k], 32);
    }
    if (sub == 0) {
        float di = dvg[nl];
        float sw = 2.0f * di * di;
        U8 hv; hv.u = *(const uint4*)&hg[nl * 128 + cl8];
        const float* bb = (cl8 < 64) ? &ba[cl8] : &bx[cl8 - 64];
        U8 pk;
        #pragma unroll
        for (int k = 0; k < 4; k++) {
            float2 f = __half22float2(hv.h[k]);
            float ox = fmaxf(di * acc[2 * k]     + sw * f.x + bb[2 * k],     0.0f);
            float oy = fmaxf(di * acc[2 * k + 1] + sw * f.y + bb[2 * k + 1], 0.0f);
            pk.h[k] = __floats2half2_rn(ox, oy);
        }
        *(uint4*)&outB16[wid * 128 + cl8] = pk.u;
    }
}

// ---------------- Aggregation, 64 channels (layer 2), fp16 gather ----------------

__global__ __launch_bounds__(256) void k_agg64(const unsigned short* __restrict__ g16,
                                               const int* __restrict__ rowptr,
                                               const unsigned short* __restrict__ ssrc,
                                               const float* __restrict__ dinv,
                                               const float* __restrict__ ba2,
                                               const float* __restrict__ bx2,
                                               float* __restrict__ s2) {
    int xcd = blockIdx.x & 7, slot = blockIdx.x >> 3;
    int gi = slot / 250, chunk = slot - gi * 250;
    int g = xcd + 8 * gi;
    if (g >= NB) return;
    int nl   = chunk * 4 + (threadIdx.x >> 6);
    int wid  = g * NPG + nl;
    int lane = threadIdx.x & 63;
    int sub = lane >> 3;           // 0..7: edge j%8
    int cl8 = (lane & 7) * 8;      // channel offset
    const unsigned short* hg = g16 + g * NPG * 64;
    const float* dvg = dinv + g * NPG;
    float acc[8] = {};
    union U8 { uint4 u; __half2 h[4]; };
    int e0 = rowptr[wid], e1 = rowptr[wid + 1];
    int e = e0;
    for (; e + 16 <= e1; e += 16) {
        int s[2]; float dv[2]; U8 r[2];
        #pragma unroll
        for (int j = 0; j < 2; j++) s[j] = ssrc[e + 8 * j + sub];
        #pragma unroll
        for (int j = 0; j < 2; j++) dv[j] = dvg[s[j]];
        #pragma unroll
        for (int j = 0; j < 2; j++) r[j].u = *(const uint4*)&hg[s[j] * 64 + cl8];
        #pragma unroll
        for (int j = 0; j < 2; j++) {
            #pragma unroll
            for (int k = 0; k < 4; k++) {
                float2 f = __half22float2(r[j].h[k]);
                acc[2 * k]     += dv[j] * f.x;
                acc[2 * k + 1] += dv[j] * f.y;
            }
        }
    }
    for (; e < e1; e += 8) {
        int ee = e + sub;
        int ss; float dv;
        if (ee < e1) { ss = ssrc[ee]; dv = dvg[ss]; }
        else         { ss = ssrc[e];  dv = 0.0f; }
        U8 r; r.u = *(const uint4*)&hg[ss * 64 + cl8];
        #pragma unroll
        for (int k = 0; k < 4; k++) {
            float2 f = __half22float2(r.h[k]);
            acc[2 * k]     += dv * f.x;
            acc[2 * k + 1] += dv * f.y;
        }
    }
    #pragma unroll
    for (int k = 0; k < 8; k++) {
        acc[k] += __shfl_xor(acc[k], 8);
        acc[k] += __shfl_xor(acc[k], 16);
        acc[k] += __shfl_xor(acc[k], 32);
    }
    if (sub == 0) {
        float di = dvg[nl];
        float sw = 2.0f * di * di;
        U8 hv; hv.u = *(const uint4*)&hg[nl * 64 + cl8];
        float o[8];
        #pragma unroll
        for (int k = 0; k < 4; k++) {
            float2 f = __half22float2(hv.h[k]);
            o[2 * k]     = di * acc[2 * k]     + sw * f.x;
            o[2 * k + 1] = di * acc[2 * k + 1] + sw * f.y;
        }
        if (cl8 < 32) {
            #pragma unroll
            for (int k = 0; k < 8; k++) o[k] += ba2[cl8 + k];
        } else {
            #pragma unroll
            for (int k = 0; k < 8; k++) o[k] = fmaxf(o[k] + bx2[cl8 - 32 + k], 0.0f);
        }
        *(float4*)&s2[wid * 64 + cl8]     = make_float4(o[0], o[1], o[2], o[3]);
        *(float4*)&s2[wid * 64 + cl8 + 4] = make_float4(o[4], o[5], o[6], o[7]);
    }
}

// ---------------- GEMM 2: g16 = fp16( [a1|x1] @ blockdiag(W_a2, W_x2) ) ----------------

__global__ __launch_bounds__(256) void k_gemm2(const unsigned short* __restrict__ Bm16,
                                               const float* __restrict__ Wa2,
                                               const float* __restrict__ Wx2,
                                               unsigned short* __restrict__ g16) {
    __shared__ float xs[64][132];
    __shared__ float ws[64][68];
    int xcd = blockIdx.x & 7, slot = blockIdx.x >> 3;
    int g = xcd + 8 * (slot >> 4);
    int chunk = slot & 15;
    if (g >= NB) return;
    int row0 = g * NPG + chunk * 64;   // chunk 15 spills into next graph: benign dup
    int t = threadIdx.x;
    for (int i = 0; i < 4; i++) {
        int idx = t + 256 * i;
        int k = idx >> 4, c4 = idx & 15, c = c4 * 4;
        float4 v;
        if (c < 32) v = *(const float4*)&Wa2[k * 32 + c];
        else        v = *(const float4*)&Wx2[k * 32 + (c - 32)];
        *(float4*)&ws[k][c] = v;
    }
    for (int i = 0; i < 4; i++) {
        int idx = t + 256 * i;          // 1024 uint4s = 64 rows x 16 groups
        int r = idx >> 4, c8 = idx & 15;
        int rr = row0 + r; if (rr >= N_NODES) rr = N_NODES - 1;
        union { uint4 u; __half2 h[4]; } pk;
        pk.u = *(const uint4*)&Bm16[rr * 128 + c8 * 8];
        float2 f0 = __half22float2(pk.h[0]);
        float2 f1 = __half22float2(pk.h[1]);
        float2 f2 = __half22float2(pk.h[2]);
        float2 f3 = __half22float2(pk.h[3]);
        int cb = c8 * 8;
        *(float4*)&xs[r][cb]     = make_float4(f0.x, f0.y, f1.x, f1.y);
        *(float4*)&xs[r][cb + 4] = make_float4(f2.x, f2.y, f3.x, f3.y);
    }
    __syncthreads();
    int cg = t & 15, rg = t >> 4;
    int koff = (cg < 8) ? 0 : 64;
    float acc[4][4] = {};
    for (int k = 0; k < 64; k++) {
        float4 w = *(float4*)&ws[k][cg * 4];
        float xv[4];
        for (int i = 0; i < 4; i++) xv[i] = xs[rg * 4 + i][koff + k];
        for (int i = 0; i < 4; i++) {
            acc[i][0] += xv[i] * w.x; acc[i][1] += xv[i] * w.y;
            acc[i][2] += xv[i] * w.z; acc[i][3] += xv[i] * w.w;
        }
    }
    for (int i = 0; i < 4; i++) {
        int r = row0 + rg * 4 + i;
        if (r < N_NODES) {
            union { ushort4 u; __half2 h[2]; } pk;
            pk.h[0] = __floats2half2_rn(acc[i][0], acc[i][1]);
            pk.h[1] = __floats2half2_rn(acc[i][2], acc[i][3]);
            *(ushort4*)&g16[r * 64 + cg * 4] = pk.u;
        }
    }
}

// ---------------- Segment softmax stats (cols 0..31), 512 threads ----------------

__global__ __launch_bounds__(512) void k_smax(const float* __restrict__ s2,
                                              float* __restrict__ gmax,
                                              float* __restrict__ sinv) {
    __shared__ float red[16][32];
    int g = (blockIdx.x & 7) + 8 * (blockIdx.x >> 3);
    if (g >= NB) return;
    int t = threadIdx.x;
    int c = t & 31, sub = t >> 5;     // 16 row-subsets
    size_t base = (size_t)g * NPG;
    float m = -1e30f;
    for (int n = sub; n < NPG; n += 16)
        m = fmaxf(m, s2[(base + n) * 64 + c]);
    red[sub][c] = m; __syncthreads();
    if (sub == 0) {
        for (int j = 1; j < 16; j++) m = fmaxf(m, red[j][c]);
        red[0][c] = m;
        gmax[g * 32 + c] = m;
    }
    __syncthreads();
    m = red[0][c];
    __syncthreads();
    float sum = 0.0f;
    for (int n = sub; n < NPG; n += 16)
        sum += __expf(s2[(base + n) * 64 + c] - m);
    red[sub][c] = sum; __syncthreads();
    if (sub == 0) {
        for (int j = 1; j < 16; j++) sum += red[j][c];
        sinv[g * 32 + c] = 1.0f / sum;
    }
}

// ---------------- Bilinear pool: 8 chunks/graph, 25-row tiles ----------------
// Direct per-chunk partial stores: prods[(g*8+ch)][1024]; no atomics/memset.

__global__ __launch_bounds__(256) void k_pool(const float* __restrict__ s2,
                                              const float* __restrict__ gmax,
                                              float* __restrict__ prods) {
    __shared__ float ta[25][32];
    __shared__ float tx[25][32];
    __shared__ float gm[32];
    int xcd = blockIdx.x & 7, slot = blockIdx.x >> 3;
    int g = xcd + 8 * (slot >> 3);
    int ch = slot & 7;
    if (g >= NB) return;
    int t = threadIdx.x;
    if (t < 32) gm[t] = gmax[g * 32 + t];
    int e  = t >> 3;
    int f4 = t & 7;
    float a0 = 0.f, a1 = 0.f, a2 = 0.f, a3 = 0.f;
    int base = g * NPG + ch * 125;
    for (int n0 = 0; n0 < 125; n0 += 25) {
        __syncthreads();
        for (int i = t; i < 25 * 16; i += 256) {
            int r = i >> 4, c4 = i & 15;
            float4 v = *(const float4*)&s2[(size_t)(base + n0 + r) * 64 + c4 * 4];
            if (c4 < 8) {
                int cb = c4 * 4;
                v.x = __expf(v.x - gm[cb + 0]);
                v.y = __expf(v.y - gm[cb + 1]);
                v.z = __expf(v.z - gm[cb + 2]);
                v.w = __expf(v.w - gm[cb + 3]);
                *(float4*)&ta[r][cb] = v;
            } else {
                *(float4*)&tx[r][(c4 - 8) * 4] = v;
            }
        }
        __syncthreads();
        #pragma unroll 5
        for (int n = 0; n < 25; n++) {
            float a   = ta[n][e];
            float4 xv = *(float4*)&tx[n][f4 * 4];
            a0 += a * xv.x; a1 += a * xv.y; a2 += a * xv.z; a3 += a * xv.w;
        }
    }
    *(float4*)&prods[((size_t)(g * 8 + ch)) * 1024 + e * 32 + f4 * 4] =
        make_float4(a0, a1, a2, a3);
}

// ---------------- Head: sum 8 chunk-partials, linear, softmax ----------------

__global__ __launch_bounds__(256) void k_head(const float* __restrict__ prods,
                                              const float* __restrict__ sinv,
                                              const float* __restrict__ Wlin,
                                              const float* __restrict__ blin,
                                              float* __restrict__ out) {
    __shared__ float red[4][NCLS];
    int g = (blockIdx.x & 7) + 8 * (blockIdx.x >> 3);
    if (g >= NB) return;
    int t = threadIdx.x;
    float p[NCLS];
    for (int c = 0; c < NCLS; c++) p[c] = 0.0f;
    const float* pg = &prods[(size_t)g * 8 * 1024];
    for (int j = 0; j < 4; j++) {
        int k = t * 4 + j;
        int e = k >> 5;
        float v = 0.0f;
        #pragma unroll
        for (int q = 0; q < 8; q++) v += pg[q * 1024 + k];
        v *= sinv[g * 32 + e];
        const float* wrow = &Wlin[k * NCLS];
        for (int c = 0; c < NCLS; c++) p[c] += v * wrow[c];
    }
    for (int off = 32; off > 0; off >>= 1)
        for (int c = 0; c < NCLS; c++) p[c] += __shfl_down(p[c], off, 64);
    int wave = t >> 6, lane = t & 63;
    if (lane == 0)
        for (int c = 0; c < NCLS; c++) red[wave][c] = p[c];
    __syncthreads();
    if (t == 0) {
        float logits[NCLS]; float mx = -1e30f;
        for (int c = 0; c < NCLS; c++) {
            logits[c] = red[0][c] + red[1][c] + red[2][c] + red[3][c] + blin[c];
            mx = fmaxf(mx, logits[c]);
        }
        float s = 0.0f;
        for (int c = 0; c < NCLS; c++) { logits[c] = expf(logits[c] - mx); s += logits[c]; }
        float inv = 1.0f / s;
        for (int c = 0; c < NCLS; c++) out[g * NCLS + c] = logits[c] * inv;
    }
}

// ---------------- launch ----------------

extern "C" void kernel_launch(void* const* d_in, const int* in_sizes, int n_in,
                              void* d_out, int out_size, void* d_ws, size_t ws_size,
                              hipStream_t stream) {
    const float* x    = (const float*)d_in[0];
    const int*   ei   = (const int*)d_in[1];
    const float* Wa1  = (const float*)d_in[3];
    const float* ba1  = (const float*)d_in[4];
    const float* Wa2  = (const float*)d_in[5];
    const float* ba2  = (const float*)d_in[6];
    const float* Wx1  = (const float*)d_in[7];
    const float* bx1  = (const float*)d_in[8];
    const float* Wx2  = (const float*)d_in[9];
    const float* bx2  = (const float*)d_in[10];
    const float* Wlin = (const float*)d_in[11];
    const float* blin = (const float*)d_in[12];
    float* out = (float*)d_out;

    char* w = (char*)d_ws;
    auto alloc = [&](size_t bytes) -> void* {
        void* p = (void*)w;
        w += (bytes + 255) & ~(size_t)255;
        return p;
    };
    int*            rowptr = (int*)alloc((N_NODES + 1) * sizeof(int));
    float*          dinv   = (float*)alloc(N_NODES * sizeof(float));
    unsigned short* ssrc   = (unsigned short*)alloc((size_t)N_EDGES * sizeof(unsigned short));
    float*          gmax   = (float*)alloc(NB * DE * sizeof(float));
    float*          sinv   = (float*)alloc(NB * DE * sizeof(float));
    float*          prods  = (float*)alloc((size_t)NB * 8 * 1024 * sizeof(float));
    unsigned short* h16    = (unsigned short*)alloc((size_t)N_NODES * 128 * sizeof(unsigned short));
    unsigned short* b16    = (unsigned short*)alloc((size_t)N_NODES * 128 * sizeof(unsigned short));
    unsigned short* g16    = (unsigned short*)alloc((size_t)N_NODES * 64 * sizeof(unsigned short));
    float*          s2     = (float*)alloc((size_t)N_NODES * 64 * sizeof(float));

    const int* srcp = ei;
    const int* dstp = ei + N_EDGES;

    k_sort<<<8 * 13, 1024, 0, stream>>>(srcp, dstp, rowptr, dinv, ssrc);
    k_gemm1<<<8 * 13 * 32, 256, 0, stream>>>(x, Wa1, Wx1, h16);
    k_agg128<<<8 * 13 * 250, 256, 0, stream>>>(h16, rowptr, ssrc, dinv, ba1, bx1, b16);
    k_gemm2<<<8 * 13 * 16, 256, 0, stream>>>(b16, Wa2, Wx2, g16);
    k_agg64<<<8 * 13 * 250, 256, 0, stream>>>(g16, rowptr, ssrc, dinv, ba2, bx2, s2);
    k_smax<<<8 * 13, 512, 0, stream>>>(s2, gmax, sinv);
    k_pool<<<8 * 13 * 8, 256, 0, stream>>>(s2, gmax, prods);
    k_head<<<8 * 13, 256, 0, stream>>>(prods, sinv, Wlin, blin, out);
}

// Round 14
// 349.396 us; speedup vs baseline: 1.1577x; 1.0023x over previous
//
#include <hip/hip_runtime.h>
#include <hip/hip_bf16.h>
#include <hip/hip_fp16.h>

#define N_NODES 100000
#define N_EDGES 3200000
#define NB      100
#define NPG     1000
#define EPG     32000    // edges per graph
#define DIN     128
#define DH      64
#define DE      32
#define NCLS    10

// XCD-affine swizzle: graph g lives on XCD g%8 (blockIdx%8 = dispatch
// round-robin), keeping each graph's working set in ONE XCD's 4MB L2.
// Aggregation = node-per-wave PULL gather from L2 (R7). R9/R10: single-kernel
// LDS counting sort. R11: fp16 gather rows. R12: 32-bit offsets + fp16 a1|x1.
// R13: high-parallelism un-fused tail (fused k_tail had 4% occupancy).
// R14: edge record packs (src | fp16(dinv[src])<<16) -- kills the dependent
// dinv[s] L2 load chain (R13: agg128 VALU-bound at 69%); inner product uses
// the v_fma_mix idiom (acc += dv * __half2float(h)) to fold f16 converts
// into the FMA.

// ---------------- Per-graph CSR build, entirely in LDS ----------------
// Output edge record: uint32 = src_local | (fp16(dinv[src]) << 16).

__global__ __launch_bounds__(1024) void k_sort(const int* __restrict__ src,
                                               const int* __restrict__ dst,
                                               int* __restrict__ rowptr,
                                               float* __restrict__ dinv,
                                               unsigned int* __restrict__ esrc) {
    __shared__ __align__(16) unsigned short buf[EPG];  // 64 KB sorted src idx
    __shared__ int cnt[NPG];
    __shared__ int pre[NPG];
    __shared__ int sm[1024];
    __shared__ unsigned short dh[NPG];                  // fp16 dinv
    int g = (blockIdx.x & 7) + 8 * (blockIdx.x >> 3);
    if (g >= NB) return;
    int t = threadIdx.x;
    int ebase = g * EPG, nbase = g * NPG;
    if (t < NPG) cnt[t] = 0;
    __syncthreads();
    for (int i = t; i < EPG; i += 1024)
        atomicAdd(&cnt[dst[ebase + i] - nbase], 1);
    __syncthreads();
    int v = (t < NPG) ? cnt[t] : 0;
    if (t < NPG) {
        float dv = rsqrtf((float)v + 2.0f);
        dinv[nbase + t] = dv;
        dh[t] = __half_as_ushort(__float2half_rn(dv));
    }
    sm[t] = v;
    __syncthreads();
    for (int off = 1; off < 1024; off <<= 1) {
        int x = (t >= off) ? sm[t - off] : 0;
        __syncthreads();
        sm[t] += x;
        __syncthreads();
    }
    if (t < NPG) {
        int ex = sm[t] - v;
        pre[t] = ex;
        rowptr[nbase + t] = ebase + ex;
    }
    if (g == NB - 1 && t == 0) rowptr[N_NODES] = N_EDGES;
    __syncthreads();
    for (int i = t; i < EPG; i += 1024) {
        int e = ebase + i;
        int d = dst[e] - nbase;
        int s = src[e] - nbase;
        int pos = atomicAdd(&pre[d], 1);
        buf[pos] = (unsigned short)s;
    }
    __syncthreads();
    // pack + coalesced 16B/lane writeout (4 edges per uint4)
    uint4* gout = (uint4*)(esrc + ebase);
    const ushort4* lbuf = (const ushort4*)buf;
    for (int i = t; i < EPG / 4; i += 1024) {
        ushort4 s4 = lbuf[i];
        uint4 o;
        o.x = s4.x | ((unsigned)dh[s4.x] << 16);
        o.y = s4.y | ((unsigned)dh[s4.y] << 16);
        o.z = s4.z | ((unsigned)dh[s4.z] << 16);
        o.w = s4.w | ((unsigned)dh[s4.w] << 16);
        gout[i] = o;
    }
}

// ---------------- GEMM 1: h16 = fp16( x @ [W_a1 | W_x1] ) ----------------

__global__ __launch_bounds__(256) void k_gemm1(const float* __restrict__ x,
                                               const float* __restrict__ Wa,
                                               const float* __restrict__ Wx,
                                               unsigned short* __restrict__ h16) {
    __shared__ float xs[32][128];
    __shared__ float ws[32][128];
    int xcd = blockIdx.x & 7, slot = blockIdx.x >> 3;
    int g = xcd + 8 * (slot >> 5);
    int chunk = slot & 31;
    if (g >= NB) return;
    int row0 = g * NPG + chunk * 32;
    int t = threadIdx.x;
    for (int i = 0; i < 4; i++) {
        int idx = t + 256 * i;
        int r = idx >> 5, k4 = idx & 31;
        int rr = row0 + r; if (rr >= N_NODES) rr = N_NODES - 1;
        *(float4*)&xs[r][k4 * 4] = *(const float4*)&x[(size_t)rr * 128 + k4 * 4];
    }
    float acc[4][4] = {};
    int rg = t >> 5, cg = t & 31;
    for (int kt = 0; kt < 4; kt++) {
        __syncthreads();
        for (int i = 0; i < 4; i++) {
            int idx = t + 256 * i;
            int kk = idx >> 5, c4 = idx & 31;
            int k = kt * 32 + kk, c = c4 * 4;
            float4 v;
            if (c < 64) v = *(const float4*)&Wa[k * 64 + c];
            else        v = *(const float4*)&Wx[k * 64 + (c - 64)];
            *(float4*)&ws[kk][c] = v;
        }
        __syncthreads();
        for (int kk = 0; kk < 32; kk++) {
            float4 w = *(float4*)&ws[kk][cg * 4];
            float xv[4];
            for (int i = 0; i < 4; i++) xv[i] = xs[rg * 4 + i][kt * 32 + kk];
            for (int i = 0; i < 4; i++) {
                acc[i][0] += xv[i] * w.x; acc[i][1] += xv[i] * w.y;
                acc[i][2] += xv[i] * w.z; acc[i][3] += xv[i] * w.w;
            }
        }
    }
    for (int i = 0; i < 4; i++) {
        int r = row0 + rg * 4 + i;
        if (r < N_NODES) {
            union { ushort4 u; __half2 h[2]; } pk;
            pk.h[0] = __floats2half2_rn(acc[i][0], acc[i][1]);
            pk.h[1] = __floats2half2_rn(acc[i][2], acc[i][3]);
            *(ushort4*)&h16[r * 128 + cg * 4] = pk.u;
        }
    }
}

// ---------------- Aggregation, 128 channels (layer 1) ----------------
// Wave = 1 node; sub 0..3 edge-parallel; cl8 = 8-ch 16B group.
// Packed edge record: one load gives src idx + fp16 coef half.

__global__ __launch_bounds__(256) void k_agg128(const unsigned short* __restrict__ h16,
                                                const int* __restrict__ rowptr,
                                                const unsigned int* __restrict__ esrc,
                                                const float* __restrict__ dinv,
                                                const float* __restrict__ ba,
                                                const float* __restrict__ bx,
                                                unsigned short* __restrict__ outB16) {
    int xcd = blockIdx.x & 7, slot = blockIdx.x >> 3;
    int gi = slot / 250, chunk = slot - gi * 250;
    int g = xcd + 8 * gi;
    if (g >= NB) return;
    int nl   = chunk * 4 + (threadIdx.x >> 6);   // local node 0..999
    int wid  = g * NPG + nl;
    int lane = threadIdx.x & 63;
    int sub = lane >> 4;           // 0..3: edge j%4
    int cl8 = (lane & 15) * 8;     // channel offset of this lane's 16B group
    const unsigned short* hg = h16 + g * NPG * 128;
    float acc[8] = {};
    union U8 { uint4 u; __half h[8]; };
    int e0 = rowptr[wid], e1 = rowptr[wid + 1];
    int e = e0;
    for (; e + 16 <= e1; e += 16) {
        unsigned pv[4]; U8 r[4];
        #pragma unroll
        for (int j = 0; j < 4; j++) pv[j] = esrc[e + 4 * j + sub];
        #pragma unroll
        for (int j = 0; j < 4; j++) r[j].u = *(const uint4*)&hg[(pv[j] & 0xffffu) * 128 + cl8];
        #pragma unroll
        for (int j = 0; j < 4; j++) {
            float dv = __half2float(__ushort_as_half((unsigned short)(pv[j] >> 16)));
            #pragma unroll
            for (int k = 0; k < 8; k++)
                acc[k] += dv * __half2float(r[j].h[k]);
        }
    }
    for (; e + 8 <= e1; e += 8) {
        #pragma unroll
        for (int j = 0; j < 2; j++) {
            unsigned pv = esrc[e + 4 * j + sub];
            U8 r; r.u = *(const uint4*)&hg[(pv & 0xffffu) * 128 + cl8];
            float dv = __half2float(__ushort_as_half((unsigned short)(pv >> 16)));
            #pragma unroll
            for (int k = 0; k < 8; k++)
                acc[k] += dv * __half2float(r.h[k]);
        }
    }
    for (; e < e1; e += 4) {
        int ee = e + sub;
        unsigned pv; float scale;
        if (ee < e1) { pv = esrc[ee]; scale = 1.0f; }
        else         { pv = esrc[e];  scale = 0.0f; }
        U8 r; r.u = *(const uint4*)&hg[(pv & 0xffffu) * 128 + cl8];
        float dv = scale * __half2float(__ushort_as_half((unsigned short)(pv >> 16)));
        #pragma unroll
        for (int k = 0; k < 8; k++)
            acc[k] += dv * __half2float(r.h[k]);
    }
    #pragma unroll
    for (int k = 0; k < 8; k++) {
        acc[k] += __shfl_xor(acc[k], 16);
        acc[k] += __shfl_xor(acc[k], 32);
    }
    if (sub == 0) {
        float di = dinv[wid];
        float sw = 2.0f * di * di;
        U8 hv; hv.u = *(const uint4*)&hg[nl * 128 + cl8];
        const float* bb = (cl8 < 64) ? &ba[cl8] : &bx[cl8 - 64];
        union { ushort4 u[2]; __half2 h[4]; uint4 q; } pk;
        #pragma unroll
        for (int k = 0; k < 4; k++) {
            float ox = fmaxf(di * acc[2 * k]     + sw * __half2float(hv.h[2 * k])     + bb[2 * k],     0.0f);
            float oy = fmaxf(di * acc[2 * k + 1] + sw * __half2float(hv.h[2 * k + 1]) + bb[2 * k + 1], 0.0f);
            pk.h[k] = __floats2half2_rn(ox, oy);
        }
        *(uint4*)&outB16[wid * 128 + cl8] = pk.q;
    }
}

// ---------------- Aggregation, 64 channels (layer 2) ----------------
// sub 0..7 edge-parallel; cl8 = 8-ch group. fp32 out.
// cg<32: a-branch (+b_a2, no relu); cg>=32: x-branch (+b_x2, relu).

__global__ __launch_bounds__(256) void k_agg64(const unsigned short* __restrict__ g16,
                                               const int* __restrict__ rowptr,
                                               const unsigned int* __restrict__ esrc,
                                               const float* __restrict__ dinv,
                                               const float* __restrict__ ba2,
                                               const float* __restrict__ bx2,
                                               float* __restrict__ s2) {
    int xcd = blockIdx.x & 7, slot = blockIdx.x >> 3;
    int gi = slot / 250, chunk = slot - gi * 250;
    int g = xcd + 8 * gi;
    if (g >= NB) return;
    int nl   = chunk * 4 + (threadIdx.x >> 6);
    int wid  = g * NPG + nl;
    int lane = threadIdx.x & 63;
    int sub = lane >> 3;           // 0..7: edge j%8
    int cl8 = (lane & 7) * 8;      // channel offset
    const unsigned short* hg = g16 + g * NPG * 64;
    float acc[8] = {};
    union U8 { uint4 u; __half h[8]; };
    int e0 = rowptr[wid], e1 = rowptr[wid + 1];
    int e = e0;
    for (; e + 16 <= e1; e += 16) {
        unsigned pv[2]; U8 r[2];
        #pragma unroll
        for (int j = 0; j < 2; j++) pv[j] = esrc[e + 8 * j + sub];
        #pragma unroll
        for (int j = 0; j < 2; j++) r[j].u = *(const uint4*)&hg[(pv[j] & 0xffffu) * 64 + cl8];
        #pragma unroll
        for (int j = 0; j < 2; j++) {
            float dv = __half2float(__ushort_as_half((unsigned short)(pv[j] >> 16)));
            #pragma unroll
            for (int k = 0; k < 8; k++)
                acc[k] += dv * __half2float(r[j].h[k]);
        }
    }
    for (; e < e1; e += 8) {
        int ee = e + sub;
        unsigned pv; float scale;
        if (ee < e1) { pv = esrc[ee]; scale = 1.0f; }
        else         { pv = esrc[e];  scale = 0.0f; }
        U8 r; r.u = *(const uint4*)&hg[(pv & 0xffffu) * 64 + cl8];
        float dv = scale * __half2float(__ushort_as_half((unsigned short)(pv >> 16)));
        #pragma unroll
        for (int k = 0; k < 8; k++)
            acc[k] += dv * __half2float(r.h[k]);
    }
    #pragma unroll
    for (int k = 0; k < 8; k++) {
        acc[k] += __shfl_xor(acc[k], 8);
        acc[k] += __shfl_xor(acc[k], 16);
        acc[k] += __shfl_xor(acc[k], 32);
    }
    if (sub == 0) {
        float di = dinv[wid];
        float sw = 2.0f * di * di;
        U8 hv; hv.u = *(const uint4*)&hg[nl * 64 + cl8];
        float o[8];
        #pragma unroll
        for (int k = 0; k < 8; k++)
            o[k] = di * acc[k] + sw * __half2float(hv.h[k]);
        if (cl8 < 32) {
            #pragma unroll
            for (int k = 0; k < 8; k++) o[k] += ba2[cl8 + k];
        } else {
            #pragma unroll
            for (int k = 0; k < 8; k++) o[k] = fmaxf(o[k] + bx2[cl8 - 32 + k], 0.0f);
        }
        *(float4*)&s2[wid * 64 + cl8]     = make_float4(o[0], o[1], o[2], o[3]);
        *(float4*)&s2[wid * 64 + cl8 + 4] = make_float4(o[4], o[5], o[6], o[7]);
    }
}

// ---------------- GEMM 2: g16 = fp16( [a1|x1] @ blockdiag(W_a2, W_x2) ) ----------------

__global__ __launch_bounds__(256) void k_gemm2(const unsigned short* __restrict__ Bm16,
                                               const float* __restrict__ Wa2,
                                               const float* __restrict__ Wx2,
                                               unsigned short* __restrict__ g16) {
    __shared__ float xs[64][132];
    __shared__ float ws[64][68];
    int xcd = blockIdx.x & 7, slot = blockIdx.x >> 3;
    int g = xcd + 8 * (slot >> 4);
    int chunk = slot & 15;
    if (g >= NB) return;
    int row0 = g * NPG + chunk * 64;   // chunk 15 spills into next graph: benign dup
    int t = threadIdx.x;
    for (int i = 0; i < 4; i++) {
        int idx = t + 256 * i;
        int k = idx >> 4, c4 = idx & 15, c = c4 * 4;
        float4 v;
        if (c < 32) v = *(const float4*)&Wa2[k * 32 + c];
        else        v = *(const float4*)&Wx2[k * 32 + (c - 32)];
        *(float4*)&ws[k][c] = v;
    }
    for (int i = 0; i < 4; i++) {
        int idx = t + 256 * i;          // 1024 uint4s = 64 rows x 16 groups
        int r = idx >> 4, c8 = idx & 15;
        int rr = row0 + r; if (rr >= N_NODES) rr = N_NODES - 1;
        union { uint4 u; __half2 h[4]; } pk;
        pk.u = *(const uint4*)&Bm16[rr * 128 + c8 * 8];
        float2 f0 = __half22float2(pk.h[0]);
        float2 f1 = __half22float2(pk.h[1]);
        float2 f2 = __half22float2(pk.h[2]);
        float2 f3 = __half22float2(pk.h[3]);
        int cb = c8 * 8;
        *(float4*)&xs[r][cb]     = make_float4(f0.x, f0.y, f1.x, f1.y);
        *(float4*)&xs[r][cb + 4] = make_float4(f2.x, f2.y, f3.x, f3.y);
    }
    __syncthreads();
    int cg = t & 15, rg = t >> 4;
    int koff = (cg < 8) ? 0 : 64;
    float acc[4][4] = {};
    for (int k = 0; k < 64; k++) {
        float4 w = *(float4*)&ws[k][cg * 4];
        float xv[4];
        for (int i = 0; i < 4; i++) xv[i] = xs[rg * 4 + i][koff + k];
        for (int i = 0; i < 4; i++) {
            acc[i][0] += xv[i] * w.x; acc[i][1] += xv[i] * w.y;
            acc[i][2] += xv[i] * w.z; acc[i][3] += xv[i] * w.w;
        }
    }
    for (int i = 0; i < 4; i++) {
        int r = row0 + rg * 4 + i;
        if (r < N_NODES) {
            union { ushort4 u; __half2 h[2]; } pk;
            pk.h[0] = __floats2half2_rn(acc[i][0], acc[i][1]);
            pk.h[1] = __floats2half2_rn(acc[i][2], acc[i][3]);
            *(ushort4*)&g16[r * 64 + cg * 4] = pk.u;
        }
    }
}

// ---------------- Segment softmax stats (cols 0..31), 512 threads ----------------

__global__ __launch_bounds__(512) void k_smax(const float* __restrict__ s2,
                                              float* __restrict__ gmax,
                                              float* __restrict__ sinv) {
    __shared__ float red[16][32];
    int g = (blockIdx.x & 7) + 8 * (blockIdx.x >> 3);
    if (g >= NB) return;
    int t = threadIdx.x;
    int c = t & 31, sub = t >> 5;     // 16 row-subsets
    size_t base = (size_t)g * NPG;
    float m = -1e30f;
    for (int n = sub; n < NPG; n += 16)
        m = fmaxf(m, s2[(base + n) * 64 + c]);
    red[sub][c] = m; __syncthreads();
    if (sub == 0) {
        for (int j = 1; j < 16; j++) m = fmaxf(m, red[j][c]);
        red[0][c] = m;
        gmax[g * 32 + c] = m;
    }
    __syncthreads();
    m = red[0][c];
    __syncthreads();
    float sum = 0.0f;
    for (int n = sub; n < NPG; n += 16)
        sum += __expf(s2[(base + n) * 64 + c] - m);
    red[sub][c] = sum; __syncthreads();
    if (sub == 0) {
        for (int j = 1; j < 16; j++) sum += red[j][c];
        sinv[g * 32 + c] = 1.0f / sum;
    }
}

// ---------------- Bilinear pool: 8 chunks/graph, 25-row tiles ----------------

__global__ __launch_bounds__(256) void k_pool(const float* __restrict__ s2,
                                              const float* __restrict__ gmax,
                                              float* __restrict__ prods) {
    __shared__ float ta[25][32];
    __shared__ float tx[25][32];
    __shared__ float gm[32];
    int xcd = blockIdx.x & 7, slot = blockIdx.x >> 3;
    int g = xcd + 8 * (slot >> 3);
    int ch = slot & 7;
    if (g >= NB) return;
    int t = threadIdx.x;
    if (t < 32) gm[t] = gmax[g * 32 + t];
    int e  = t >> 3;
    int f4 = t & 7;
    float a0 = 0.f, a1 = 0.f, a2 = 0.f, a3 = 0.f;
    int base = g * NPG + ch * 125;
    for (int n0 = 0; n0 < 125; n0 += 25) {
        __syncthreads();
        for (int i = t; i < 25 * 16; i += 256) {
            int r = i >> 4, c4 = i & 15;
            float4 v = *(const float4*)&s2[(size_t)(base + n0 + r) * 64 + c4 * 4];
            if (c4 < 8) {
                int cb = c4 * 4;
                v.x = __expf(v.x - gm[cb + 0]);
                v.y = __expf(v.y - gm[cb + 1]);
                v.z = __expf(v.z - gm[cb + 2]);
                v.w = __expf(v.w - gm[cb + 3]);
                *(float4*)&ta[r][cb] = v;
            } else {
                *(float4*)&tx[r][(c4 - 8) * 4] = v;
            }
        }
        __syncthreads();
        #pragma unroll 5
        for (int n = 0; n < 25; n++) {
            float a   = ta[n][e];
            float4 xv = *(float4*)&tx[n][f4 * 4];
            a0 += a * xv.x; a1 += a * xv.y; a2 += a * xv.z; a3 += a * xv.w;
        }
    }
    *(float4*)&prods[((size_t)(g * 8 + ch)) * 1024 + e * 32 + f4 * 4] =
        make_float4(a0, a1, a2, a3);
}

// ---------------- Head: sum 8 chunk-partials, linear, softmax ----------------

__global__ __launch_bounds__(256) void k_head(const float* __restrict__ prods,
                                              const float* __restrict__ sinv,
                                              const float* __restrict__ Wlin,
                                              const float* __restrict__ blin,
                                              float* __restrict__ out) {
    __shared__ float red[4][NCLS];
    int g = (blockIdx.x & 7) + 8 * (blockIdx.x >> 3);
    if (g >= NB) return;
    int t = threadIdx.x;
    float p[NCLS];
    for (int c = 0; c < NCLS; c++) p[c] = 0.0f;
    const float* pg = &prods[(size_t)g * 8 * 1024];
    for (int j = 0; j < 4; j++) {
        int k = t * 4 + j;
        int e = k >> 5;
        float v = 0.0f;
        #pragma unroll
        for (int q = 0; q < 8; q++) v += pg[q * 1024 + k];
        v *= sinv[g * 32 + e];
        const float* wrow = &Wlin[k * NCLS];
        for (int c = 0; c < NCLS; c++) p[c] += v * wrow[c];
    }
    for (int off = 32; off > 0; off >>= 1)
        for (int c = 0; c < NCLS; c++) p[c] += __shfl_down(p[c], off, 64);
    int wave = t >> 6, lane = t & 63;
    if (lane == 0)
        for (int c = 0; c < NCLS; c++) red[wave][c] = p[c];
    __syncthreads();
    if (t == 0) {
        float logits[NCLS]; float mx = -1e30f;
        for (int c = 0; c < NCLS; c++) {
            logits[c] = red[0][c] + red[1][c] + red[2][c] + red[3][c] + blin[c];
            mx = fmaxf(mx, logits[c]);
        }
        float s = 0.0f;
        for (int c = 0; c < NCLS; c++) { logits[c] = expf(logits[c] - mx); s += logits[c]; }
        float inv = 1.0f / s;
        for (int c = 0; c < NCLS; c++) out[g * NCLS + c] = logits[c] * inv;
    }
}

// ---------------- launch ----------------

extern "C" void kernel_launch(void* const* d_in, const int* in_sizes, int n_in,
                              void* d_out, int out_size, void* d_ws, size_t ws_size,
                              hipStream_t stream) {
    const float* x    = (const float*)d_in[0];
    const int*   ei   = (const int*)d_in[1];
    const float* Wa1  = (const float*)d_in[3];
    const float* ba1  = (const float*)d_in[4];
    const float* Wa2  = (const float*)d_in[5];
    const float* ba2  = (const float*)d_in[6];
    const float* Wx1  = (const float*)d_in[7];
    const float* bx1  = (const float*)d_in[8];
    const float* Wx2  = (const float*)d_in[9];
    const float* bx2  = (const float*)d_in[10];
    const float* Wlin = (const float*)d_in[11];
    const float* blin = (const float*)d_in[12];
    float* out = (float*)d_out;

    char* w = (char*)d_ws;
    auto alloc = [&](size_t bytes) -> void* {
        void* p = (void*)w;
        w += (bytes + 255) & ~(size_t)255;
        return p;
    };
    int*            rowptr = (int*)alloc((N_NODES + 1) * sizeof(int));
    float*          dinv   = (float*)alloc(N_NODES * sizeof(float));
    unsigned int*   esrc   = (unsigned int*)alloc((size_t)N_EDGES * sizeof(unsigned int));
    float*          gmax   = (float*)alloc(NB * DE * sizeof(float));
    float*          sinv   = (float*)alloc(NB * DE * sizeof(float));
    float*          prods  = (float*)alloc((size_t)NB * 8 * 1024 * sizeof(float));
    unsigned short* h16    = (unsigned short*)alloc((size_t)N_NODES * 128 * sizeof(unsigned short));
    unsigned short* b16    = (unsigned short*)alloc((size_t)N_NODES * 128 * sizeof(unsigned short));
    unsigned short* g16    = (unsigned short*)alloc((size_t)N_NODES * 64 * sizeof(unsigned short));
    float*          s2     = (float*)alloc((size_t)N_NODES * 64 * sizeof(float));

    const int* srcp = ei;
    const int* dstp = ei + N_EDGES;

    k_sort<<<8 * 13, 1024, 0, stream>>>(srcp, dstp, rowptr, dinv, esrc);
    k_gemm1<<<8 * 13 * 32, 256, 0, stream>>>(x, Wa1, Wx1, h16);
    k_agg128<<<8 * 13 * 250, 256, 0, stream>>>(h16, rowptr, esrc, dinv, ba1, bx1, b16);
    k_gemm2<<<8 * 13 * 16, 256, 0, stream>>>(b16, Wa2, Wx2, g16);
    k_agg64<<<8 * 13 * 250, 256, 0, stream>>>(g16, rowptr, esrc, dinv, ba2, bx2, s2);
    k_smax<<<8 * 13, 512, 0, stream>>>(s2, gmax, sinv);
    k_pool<<<8 * 13 * 8, 256, 0, stream>>>(s2, gmax, prods);
    k_head<<<8 * 13, 256, 0, stream>>>(prods, sinv, Wlin, blin, out);
}

// Round 15
// 312.854 us; speedup vs baseline: 1.2929x; 1.1168x over previous
//
#include <hip/hip_runtime.h>
#include <hip/hip_bf16.h>
#include <hip/hip_fp16.h>

#define N_NODES 100000
#define N_EDGES 3200000
#define NB      100
#define NPG     1000
#define EPG     32000    // edges per graph
#define DIN     128
#define DH      64
#define DE      32
#define NCLS    10
#define SORT_BLOCKS 104  // 8*13

// XCD-affine swizzle: graph g lives on XCD g%8 (blockIdx%8 = dispatch
// round-robin), keeping each graph's working set in ONE XCD's 4MB L2.
// Aggregation = node-per-wave PULL gather from L2 (R7). R9/R10: single-kernel
// LDS counting sort. R11: fp16 gather rows. R12: 32-bit offsets + fp16 a1|x1.
// R13: high-parallelism un-fused tail. R14: packed (src|fp16 dinv) edge recs.
// R15: (a) sort and gemm1 are independent -> fused into ONE heterogeneous
// 1024-thread launch (sort's latency-bound blocks hide behind gemm1's
// compute); (b) edge record stores src*16 (uint4-granule offset) so agg
// addressing is and+add only.

// ---------------- Fused: per-graph LDS counting sort  +  GEMM1 ----------------
// blocks [0,104): sort graph g.  blocks [104, 104+832): gemm1, 128 rows each
// (4 quarters of 256 threads; shared weight tile). Edge record:
// uint32 = (src_local*16) | (fp16(dinv[src]) << 16).

union SharedU {
    struct {
        __align__(16) unsigned short buf[EPG];   // 64000
        int cnt[NPG];                            // 4000
        int pre[NPG];                            // 4000
        int sm[1024];                            // 4096
        unsigned short dh[NPG];                  // 2000
    } so;
    struct {
        float xs[4][32][128];                    // 65536
        float ws[32][128];                       // 16384
    } ge;
};

__global__ __launch_bounds__(1024) void k_sg(const int* __restrict__ src,
                                             const int* __restrict__ dst,
                                             const float* __restrict__ x,
                                             const float* __restrict__ Wa,
                                             const float* __restrict__ Wx,
                                             int* __restrict__ rowptr,
                                             float* __restrict__ dinv,
                                             unsigned int* __restrict__ esrc,
                                             unsigned short* __restrict__ h16) {
    __shared__ SharedU S;
    int t = threadIdx.x;
    if (blockIdx.x < SORT_BLOCKS) {
        // ---------------- sort path ----------------
        int g = (blockIdx.x & 7) + 8 * (blockIdx.x >> 3);
        if (g >= NB) return;
        int ebase = g * EPG, nbase = g * NPG;
        if (t < NPG) S.so.cnt[t] = 0;
        __syncthreads();
        for (int i = t; i < EPG; i += 1024)
            atomicAdd(&S.so.cnt[dst[ebase + i] - nbase], 1);
        __syncthreads();
        int v = (t < NPG) ? S.so.cnt[t] : 0;
        if (t < NPG) {
            float dv = rsqrtf((float)v + 2.0f);
            dinv[nbase + t] = dv;
            S.so.dh[t] = __half_as_ushort(__float2half_rn(dv));
        }
        S.so.sm[t] = v;
        __syncthreads();
        for (int off = 1; off < 1024; off <<= 1) {
            int xx = (t >= off) ? S.so.sm[t - off] : 0;
            __syncthreads();
            S.so.sm[t] += xx;
            __syncthreads();
        }
        if (t < NPG) {
            int ex = S.so.sm[t] - v;
            S.so.pre[t] = ex;
            rowptr[nbase + t] = ebase + ex;
        }
        if (g == NB - 1 && t == 0) rowptr[N_NODES] = N_EDGES;
        __syncthreads();
        for (int i = t; i < EPG; i += 1024) {
            int e = ebase + i;
            int d = dst[e] - nbase;
            int s = src[e] - nbase;
            int pos = atomicAdd(&S.so.pre[d], 1);
            S.so.buf[pos] = (unsigned short)s;
        }
        __syncthreads();
        // pack (src*16 | fp16dinv<<16) + coalesced writeout
        uint4* gout = (uint4*)(esrc + ebase);
        const ushort4* lbuf = (const ushort4*)S.so.buf;
        for (int i = t; i < EPG / 4; i += 1024) {
            ushort4 s4 = lbuf[i];
            uint4 o;
            o.x = ((unsigned)s4.x * 16) | ((unsigned)S.so.dh[s4.x] << 16);
            o.y = ((unsigned)s4.y * 16) | ((unsigned)S.so.dh[s4.y] << 16);
            o.z = ((unsigned)s4.z * 16) | ((unsigned)S.so.dh[s4.z] << 16);
            o.w = ((unsigned)s4.w * 16) | ((unsigned)S.so.dh[s4.w] << 16);
            gout[i] = o;
        }
    } else {
        // ---------------- gemm1 path: h16 = fp16( x @ [W_a1 | W_x1] ) ----------------
        int b = blockIdx.x - SORT_BLOCKS;          // 8*13*8 blocks
        int xcd = b & 7, slot = b >> 3;
        int g = xcd + 8 * (slot >> 3);
        int chunk = slot & 7;                       // 8 x 128-row chunks/graph
        if (g >= NB) return;
        int q  = t >> 8;                            // quarter 0..3 (32-row tile)
        int tq = t & 255;
        int row0 = g * NPG + chunk * 128 + q * 32;  // spill rows: benign dup
        for (int i = 0; i < 4; i++) {
            int idx = tq + 256 * i;
            int r = idx >> 5, k4 = idx & 31;
            int rr = row0 + r; if (rr >= N_NODES) rr = N_NODES - 1;
            *(float4*)&S.ge.xs[q][r][k4 * 4] = *(const float4*)&x[(size_t)rr * 128 + k4 * 4];
        }
        float acc[4][4] = {};
        int rg = tq >> 5, cg = tq & 31;
        for (int kt = 0; kt < 4; kt++) {
            __syncthreads();
            {   // 1024 threads stage 1024 float4s of W
                int kk = t >> 5, c4 = t & 31;
                int k = kt * 32 + kk, c = c4 * 4;
                float4 v;
                if (c < 64) v = *(const float4*)&Wa[k * 64 + c];
                else        v = *(const float4*)&Wx[k * 64 + (c - 64)];
                *(float4*)&S.ge.ws[kk][c] = v;
            }
            __syncthreads();
            for (int kk = 0; kk < 32; kk++) {
                float4 w = *(float4*)&S.ge.ws[kk][cg * 4];
                float xv[4];
                for (int i = 0; i < 4; i++) xv[i] = S.ge.xs[q][rg * 4 + i][kt * 32 + kk];
                for (int i = 0; i < 4; i++) {
                    acc[i][0] += xv[i] * w.x; acc[i][1] += xv[i] * w.y;
                    acc[i][2] += xv[i] * w.z; acc[i][3] += xv[i] * w.w;
                }
            }
        }
        for (int i = 0; i < 4; i++) {
            int r = row0 + rg * 4 + i;
            if (r < N_NODES) {
                union { ushort4 u; __half2 h[2]; } pk;
                pk.h[0] = __floats2half2_rn(acc[i][0], acc[i][1]);
                pk.h[1] = __floats2half2_rn(acc[i][2], acc[i][3]);
                *(ushort4*)&h16[r * 128 + cg * 4] = pk.u;
            }
        }
    }
}

// ---------------- Aggregation, 128 channels (layer 1) ----------------
// Wave = 1 node; sub 0..3 edge-parallel; cl = uint4 channel group 0..15.
// Edge record gives pre-scaled uint4 offset + fp16 coef in one load.

__global__ __launch_bounds__(256) void k_agg128(const unsigned short* __restrict__ h16,
                                                const int* __restrict__ rowptr,
                                                const unsigned int* __restrict__ esrc,
                                                const float* __restrict__ dinv,
                                                const float* __restrict__ ba,
                                                const float* __restrict__ bx,
                                                unsigned short* __restrict__ outB16) {
    int xcd = blockIdx.x & 7, slot = blockIdx.x >> 3;
    int gi = slot / 250, chunk = slot - gi * 250;
    int g = xcd + 8 * gi;
    if (g >= NB) return;
    int nl   = chunk * 4 + (threadIdx.x >> 6);   // local node 0..999
    int wid  = g * NPG + nl;
    int lane = threadIdx.x & 63;
    int sub = lane >> 4;           // 0..3: edge j%4
    int cl  = lane & 15;           // uint4 channel group
    const uint4* hg4 = (const uint4*)(h16 + g * NPG * 128);
    float acc[8] = {};
    union U8 { uint4 u; __half h[8]; };
    int e0 = rowptr[wid], e1 = rowptr[wid + 1];
    int e = e0;
    for (; e + 16 <= e1; e += 16) {
        unsigned pv[4]; U8 r[4];
        #pragma unroll
        for (int j = 0; j < 4; j++) pv[j] = esrc[e + 4 * j + sub];
        #pragma unroll
        for (int j = 0; j < 4; j++) r[j].u = hg4[(pv[j] & 0xffffu) + cl];
        #pragma unroll
        for (int j = 0; j < 4; j++) {
            float dv = __half2float(__ushort_as_half((unsigned short)(pv[j] >> 16)));
            #pragma unroll
            for (int k = 0; k < 8; k++)
                acc[k] += dv * __half2float(r[j].h[k]);
        }
    }
    for (; e + 8 <= e1; e += 8) {
        #pragma unroll
        for (int j = 0; j < 2; j++) {
            unsigned pv = esrc[e + 4 * j + sub];
            U8 r; r.u = hg4[(pv & 0xffffu) + cl];
            float dv = __half2float(__ushort_as_half((unsigned short)(pv >> 16)));
            #pragma unroll
            for (int k = 0; k < 8; k++)
                acc[k] += dv * __half2float(r.h[k]);
        }
    }
    for (; e < e1; e += 4) {
        int ee = e + sub;
        unsigned pv; float scale;
        if (ee < e1) { pv = esrc[ee]; scale = 1.0f; }
        else         { pv = esrc[e];  scale = 0.0f; }
        U8 r; r.u = hg4[(pv & 0xffffu) + cl];
        float dv = scale * __half2float(__ushort_as_half((unsigned short)(pv >> 16)));
        #pragma unroll
        for (int k = 0; k < 8; k++)
            acc[k] += dv * __half2float(r.h[k]);
    }
    #pragma unroll
    for (int k = 0; k < 8; k++) {
        acc[k] += __shfl_xor(acc[k], 16);
        acc[k] += __shfl_xor(acc[k], 32);
    }
    if (sub == 0) {
        float di = dinv[wid];
        float sw = 2.0f * di * di;
        U8 hv; hv.u = hg4[nl * 16 + cl];
        int cl8 = cl * 8;
        const float* bb = (cl8 < 64) ? &ba[cl8] : &bx[cl8 - 64];
        union { __half2 h[4]; uint4 q; } pk;
        #pragma unroll
        for (int k = 0; k < 4; k++) {
            float ox = fmaxf(di * acc[2 * k]     + sw * __half2float(hv.h[2 * k])     + bb[2 * k],     0.0f);
            float oy = fmaxf(di * acc[2 * k + 1] + sw * __half2float(hv.h[2 * k + 1]) + bb[2 * k + 1], 0.0f);
            pk.h[k] = __floats2half2_rn(ox, oy);
        }
        *(uint4*)&outB16[wid * 128 + cl8] = pk.q;
    }
}

// ---------------- Aggregation, 64 channels (layer 2) ----------------
// sub 0..7 edge-parallel; cl = uint4 group 0..7; offset = (rec>>1) + cl.

__global__ __launch_bounds__(256) void k_agg64(const unsigned short* __restrict__ g16,
                                               const int* __restrict__ rowptr,
                                               const unsigned int* __restrict__ esrc,
                                               const float* __restrict__ dinv,
                                               const float* __restrict__ ba2,
                                               const float* __restrict__ bx2,
                                               float* __restrict__ s2) {
    int xcd = blockIdx.x & 7, slot = blockIdx.x >> 3;
    int gi = slot / 250, chunk = slot - gi * 250;
    int g = xcd + 8 * gi;
    if (g >= NB) return;
    int nl   = chunk * 4 + (threadIdx.x >> 6);
    int wid  = g * NPG + nl;
    int lane = threadIdx.x & 63;
    int sub = lane >> 3;           // 0..7: edge j%8
    int cl  = lane & 7;            // uint4 channel group
    const uint4* gg4 = (const uint4*)(g16 + g * NPG * 64);
    float acc[8] = {};
    union U8 { uint4 u; __half h[8]; };
    int e0 = rowptr[wid], e1 = rowptr[wid + 1];
    int e = e0;
    for (; e + 16 <= e1; e += 16) {
        unsigned pv[2]; U8 r[2];
        #pragma unroll
        for (int j = 0; j < 2; j++) pv[j] = esrc[e + 8 * j + sub];
        #pragma unroll
        for (int j = 0; j < 2; j++) r[j].u = gg4[((pv[j] & 0xffffu) >> 1) + cl];
        #pragma unroll
        for (int j = 0; j < 2; j++) {
            float dv = __half2float(__ushort_as_half((unsigned short)(pv[j] >> 16)));
            #pragma unroll
            for (int k = 0; k < 8; k++)
                acc[k] += dv * __half2float(r[j].h[k]);
        }
    }
    for (; e < e1; e += 8) {
        int ee = e + sub;
        unsigned pv; float scale;
        if (ee < e1) { pv = esrc[ee]; scale = 1.0f; }
        else         { pv = esrc[e];  scale = 0.0f; }
        U8 r; r.u = gg4[((pv & 0xffffu) >> 1) + cl];
        float dv = scale * __half2float(__ushort_as_half((unsigned short)(pv >> 16)));
        #pragma unroll
        for (int k = 0; k < 8; k++)
            acc[k] += dv * __half2float(r.h[k]);
    }
    #pragma unroll
    for (int k = 0; k < 8; k++) {
        acc[k] += __shfl_xor(acc[k], 8);
        acc[k] += __shfl_xor(acc[k], 16);
        acc[k] += __shfl_xor(acc[k], 32);
    }
    if (sub == 0) {
        float di = dinv[wid];
        float sw = 2.0f * di * di;
        U8 hv; hv.u = gg4[nl * 8 + cl];
        int cl8 = cl * 8;
        float o[8];
        #pragma unroll
        for (int k = 0; k < 8; k++)
            o[k] = di * acc[k] + sw * __half2float(hv.h[k]);
        if (cl8 < 32) {
            #pragma unroll
            for (int k = 0; k < 8; k++) o[k] += ba2[cl8 + k];
        } else {
            #pragma unroll
            for (int k = 0; k < 8; k++) o[k] = fmaxf(o[k] + bx2[cl8 - 32 + k], 0.0f);
        }
        *(float4*)&s2[wid * 64 + cl8]     = make_float4(o[0], o[1], o[2], o[3]);
        *(float4*)&s2[wid * 64 + cl8 + 4] = make_float4(o[4], o[5], o[6], o[7]);
    }
}

// ---------------- GEMM 2: g16 = fp16( [a1|x1] @ blockdiag(W_a2, W_x2) ) ----------------

__global__ __launch_bounds__(256) void k_gemm2(const unsigned short* __restrict__ Bm16,
                                               const float* __restrict__ Wa2,
                                               const float* __restrict__ Wx2,
                                               unsigned short* __restrict__ g16) {
    __shared__ float xs[64][132];
    __shared__ float ws[64][68];
    int xcd = blockIdx.x & 7, slot = blockIdx.x >> 3;
    int g = xcd + 8 * (slot >> 4);
    int chunk = slot & 15;
    if (g >= NB) return;
    int row0 = g * NPG + chunk * 64;   // chunk 15 spills into next graph: benign dup
    int t = threadIdx.x;
    for (int i = 0; i < 4; i++) {
        int idx = t + 256 * i;
        int k = idx >> 4, c4 = idx & 15, c = c4 * 4;
        float4 v;
        if (c < 32) v = *(const float4*)&Wa2[k * 32 + c];
        else        v = *(const float4*)&Wx2[k * 32 + (c - 32)];
        *(float4*)&ws[k][c] = v;
    }
    for (int i = 0; i < 4; i++) {
        int idx = t + 256 * i;          // 1024 uint4s = 64 rows x 16 groups
        int r = idx >> 4, c8 = idx & 15;
        int rr = row0 + r; if (rr >= N_NODES) rr = N_NODES - 1;
        union { uint4 u; __half2 h[4]; } pk;
        pk.u = *(const uint4*)&Bm16[rr * 128 + c8 * 8];
        float2 f0 = __half22float2(pk.h[0]);
        float2 f1 = __half22float2(pk.h[1]);
        float2 f2 = __half22float2(pk.h[2]);
        float2 f3 = __half22float2(pk.h[3]);
        int cb = c8 * 8;
        *(float4*)&xs[r][cb]     = make_float4(f0.x, f0.y, f1.x, f1.y);
        *(float4*)&xs[r][cb + 4] = make_float4(f2.x, f2.y, f3.x, f3.y);
    }
    __syncthreads();
    int cg = t & 15, rg = t >> 4;
    int koff = (cg < 8) ? 0 : 64;
    float acc[4][4] = {};
    for (int k = 0; k < 64; k++) {
        float4 w = *(float4*)&ws[k][cg * 4];
        float xv[4];
        for (int i = 0; i < 4; i++) xv[i] = xs[rg * 4 + i][koff + k];
        for (int i = 0; i < 4; i++) {
            acc[i][0] += xv[i] * w.x; acc[i][1] += xv[i] * w.y;
            acc[i][2] += xv[i] * w.z; acc[i][3] += xv[i] * w.w;
        }
    }
    for (int i = 0; i < 4; i++) {
        int r = row0 + rg * 4 + i;
        if (r < N_NODES) {
            union { ushort4 u; __half2 h[2]; } pk;
            pk.h[0] = __floats2half2_rn(acc[i][0], acc[i][1]);
            pk.h[1] = __floats2half2_rn(acc[i][2], acc[i][3]);
            *(ushort4*)&g16[r * 64 + cg * 4] = pk.u;
        }
    }
}

// ---------------- Segment softmax stats (cols 0..31), 512 threads ----------------

__global__ __launch_bounds__(512) void k_smax(const float* __restrict__ s2,
                                              float* __restrict__ gmax,
                                              float* __restrict__ sinv) {
    __shared__ float red[16][32];
    int g = (blockIdx.x & 7) + 8 * (blockIdx.x >> 3);
    if (g >= NB) return;
    int t = threadIdx.x;
    int c = t & 31, sub = t >> 5;     // 16 row-subsets
    size_t base = (size_t)g * NPG;
    float m = -1e30f;
    for (int n = sub; n < NPG; n += 16)
        m = fmaxf(m, s2[(base + n) * 64 + c]);
    red[sub][c] = m; __syncthreads();
    if (sub == 0) {
        for (int j = 1; j < 16; j++) m = fmaxf(m, red[j][c]);
        red[0][c] = m;
        gmax[g * 32 + c] = m;
    }
    __syncthreads();
    m = red[0][c];
    __syncthreads();
    float sum = 0.0f;
    for (int n = sub; n < NPG; n += 16)
        sum += __expf(s2[(base + n) * 64 + c] - m);
    red[sub][c] = sum; __syncthreads();
    if (sub == 0) {
        for (int j = 1; j < 16; j++) sum += red[j][c];
        sinv[g * 32 + c] = 1.0f / sum;
    }
}

// ---------------- Bilinear pool: 8 chunks/graph, 25-row tiles ----------------

__global__ __launch_bounds__(256) void k_pool(const float* __restrict__ s2,
                                              const float* __restrict__ gmax,
                                              float* __restrict__ prods) {
    __shared__ float ta[25][32];
    __shared__ float tx[25][32];
    __shared__ float gm[32];
    int xcd = blockIdx.x & 7, slot = blockIdx.x >> 3;
    int g = xcd + 8 * (slot >> 3);
    int ch = slot & 7;
    if (g >= NB) return;
    int t = threadIdx.x;
    if (t < 32) gm[t] = gmax[g * 32 + t];
    int e  = t >> 3;
    int f4 = t & 7;
    float a0 = 0.f, a1 = 0.f, a2 = 0.f, a3 = 0.f;
    int base = g * NPG + ch * 125;
    for (int n0 = 0; n0 < 125; n0 += 25) {
        __syncthreads();
        for (int i = t; i < 25 * 16; i += 256) {
            int r = i >> 4, c4 = i & 15;
            float4 v = *(const float4*)&s2[(size_t)(base + n0 + r) * 64 + c4 * 4];
            if (c4 < 8) {
                int cb = c4 * 4;
                v.x = __expf(v.x - gm[cb + 0]);
                v.y = __expf(v.y - gm[cb + 1]);
                v.z = __expf(v.z - gm[cb + 2]);
                v.w = __expf(v.w - gm[cb + 3]);
                *(float4*)&ta[r][cb] = v;
            } else {
                *(float4*)&tx[r][(c4 - 8) * 4] = v;
            }
        }
        __syncthreads();
        #pragma unroll 5
        for (int n = 0; n < 25; n++) {
            float a   = ta[n][e];
            float4 xv = *(float4*)&tx[n][f4 * 4];
            a0 += a * xv.x; a1 += a * xv.y; a2 += a * xv.z; a3 += a * xv.w;
        }
    }
    *(float4*)&prods[((size_t)(g * 8 + ch)) * 1024 + e * 32 + f4 * 4] =
        make_float4(a0, a1, a2, a3);
}

// ---------------- Head: sum 8 chunk-partials, linear, softmax ----------------

__global__ __launch_bounds__(256) void k_head(const float* __restrict__ prods,
                                              const float* __restrict__ sinv,
                                              const float* __restrict__ Wlin,
                                              const float* __restrict__ blin,
                                              float* __restrict__ out) {
    __shared__ float red[4][NCLS];
    int g = (blockIdx.x & 7) + 8 * (blockIdx.x >> 3);
    if (g >= NB) return;
    int t = threadIdx.x;
    float p[NCLS];
    for (int c = 0; c < NCLS; c++) p[c] = 0.0f;
    const float* pg = &prods[(size_t)g * 8 * 1024];
    for (int j = 0; j < 4; j++) {
        int k = t * 4 + j;
        int e = k >> 5;
        float v = 0.0f;
        #pragma unroll
        for (int q = 0; q < 8; q++) v += pg[q * 1024 + k];
        v *= sinv[g * 32 + e];
        const float* wrow = &Wlin[k * NCLS];
        for (int c = 0; c < NCLS; c++) p[c] += v * wrow[c];
    }
    for (int off = 32; off > 0; off >>= 1)
        for (int c = 0; c < NCLS; c++) p[c] += __shfl_down(p[c], off, 64);
    int wave = t >> 6, lane = t & 63;
    if (lane == 0)
        for (int c = 0; c < NCLS; c++) red[wave][c] = p[c];
    __syncthreads();
    if (t == 0) {
        float logits[NCLS]; float mx = -1e30f;
        for (int c = 0; c < NCLS; c++) {
            logits[c] = red[0][c] + red[1][c] + red[2][c] + red[3][c] + blin[c];
            mx = fmaxf(mx, logits[c]);
        }
        float s = 0.0f;
        for (int c = 0; c < NCLS; c++) { logits[c] = expf(logits[c] - mx); s += logits[c]; }
        float inv = 1.0f / s;
        for (int c = 0; c < NCLS; c++) out[g * NCLS + c] = logits[c] * inv;
    }
}

// ---------------- launch ----------------

extern "C" void kernel_launch(void* const* d_in, const int* in_sizes, int n_in,
                              void* d_out, int out_size, void* d_ws, size_t ws_size,
                              hipStream_t stream) {
    const float* x    = (const float*)d_in[0];
    const int*   ei   = (const int*)d_in[1];
    const float* Wa1  = (const float*)d_in[3];
    const float* ba1  = (const float*)d_in[4];
    const float* Wa2  = (const float*)d_in[5];
    const float* ba2  = (const float*)d_in[6];
    const float* Wx1  = (const float*)d_in[7];
    const float* bx1  = (const float*)d_in[8];
    const float* Wx2  = (const float*)d_in[9];
    const float* bx2  = (const float*)d_in[10];
    const float* Wlin = (const float*)d_in[11];
    const float* blin = (const float*)d_in[12];
    float* out = (float*)d_out;

    char* w = (char*)d_ws;
    auto alloc = [&](size_t bytes) -> void* {
        void* p = (void*)w;
        w += (bytes + 255) & ~(size_t)255;
        return p;
    };
    int*            rowptr = (int*)alloc((N_NODES + 1) * sizeof(int));
    float*          dinv   = (float*)alloc(N_NODES * sizeof(float));
    unsigned int*   esrc   = (unsigned int*)alloc((size_t)N_EDGES * sizeof(unsigned int));
    float*          gmax   = (float*)alloc(NB * DE * sizeof(float));
    float*          sinv   = (float*)alloc(NB * DE * sizeof(float));
    float*          prods  = (float*)alloc((size_t)NB * 8 * 1024 * sizeof(float));
    unsigned short* h16    = (unsigned short*)alloc((size_t)N_NODES * 128 * sizeof(unsigned short));
    unsigned short* b16    = (unsigned short*)alloc((size_t)N_NODES * 128 * sizeof(unsigned short));
    unsigned short* g16    = (unsigned short*)alloc((size_t)N_NODES * 64 * sizeof(unsigned short));
    float*          s2     = (float*)alloc((size_t)N_NODES * 64 * sizeof(float));

    const int* srcp = ei;
    const int* dstp = ei + N_EDGES;

    k_sg<<<SORT_BLOCKS + 8 * 13 * 8, 1024, 0, stream>>>(srcp, dstp, x, Wa1, Wx1,
                                                        rowptr, dinv, esrc, h16);
    k_agg128<<<8 * 13 * 250, 256, 0, stream>>>(h16, rowptr, esrc, dinv, ba1, bx1, b16);
    k_gemm2<<<8 * 13 * 16, 256, 0, stream>>>(b16, Wa2, Wx2, g16);
    k_agg64<<<8 * 13 * 250, 256, 0, stream>>>(g16, rowptr, esrc, dinv, ba2, bx2, s2);
    k_smax<<<8 * 13, 512, 0, stream>>>(s2, gmax, sinv);
    k_pool<<<8 * 13 * 8, 256, 0, stream>>>(s2, gmax, prods);
    k_head<<<8 * 13, 256, 0, stream>>>(prods, sinv, Wlin, blin, out);
}